// Round 8
// baseline (250.373 us; speedup 1.0000x reference)
//
#include <hip/hip_runtime.h>

// Integrate-and-fire SNN forward (IF_88957362634870).
// x: 8 frames of N = 4,194,304 fp32 (16 MiB each); out: 8 frames.
//
// R0-R7 evidence: every kernel variant caps at ~2.1-2.35 TB/s while the
// harness's contiguous 512 MB fill (regular stores) runs 6.5 TB/s. Even
// R7's fill-shaped kernel B (1 contiguous read + 1 contiguous NT write
// stream per block) failed to reach fill speed. In-flight-bytes audit
// says we are NOT concurrency-limited -> a fixed service-rate cap.
// Remaining structural difference vs the fill: nontemporal stores.
// R8 experiment (single variable): kernel B uses regular cached stores.

#define T1 8
#define T2 8
#define L_DIV 8.0f
#define EPS_C (-8e-05f)

typedef float fvec4 __attribute__((ext_vector_type(4)));

// ---------------- Kernel A: phases 1+2, x -> sc (unchanged) --------
__global__ __launch_bounds__(256) void if_phase12_kernel(
    const fvec4* __restrict__ x,
    const float* __restrict__ thresh,
    fvec4* __restrict__ sc_out,
    int n4)
{
    const int i = blockIdx.x * blockDim.x + threadIdx.x;
    const float thre = thresh[0] / L_DIV;

    const fvec4* a0 = &x[(size_t)0 * n4 + i];
    const fvec4* a1 = &x[(size_t)1 * n4 + i];
    const fvec4* a2 = &x[(size_t)2 * n4 + i];
    const fvec4* a3 = &x[(size_t)3 * n4 + i];
    const fvec4* a4 = &x[(size_t)4 * n4 + i];
    const fvec4* a5 = &x[(size_t)5 * n4 + i];
    const fvec4* a6 = &x[(size_t)6 * n4 + i];
    const fvec4* a7 = &x[(size_t)7 * n4 + i];

    fvec4 xv[T1];
    asm volatile(
        "global_load_dwordx4 %0, %8, off\n\t"
        "global_load_dwordx4 %1, %9, off\n\t"
        "global_load_dwordx4 %2, %10, off\n\t"
        "global_load_dwordx4 %3, %11, off\n\t"
        "global_load_dwordx4 %4, %12, off\n\t"
        "global_load_dwordx4 %5, %13, off\n\t"
        "global_load_dwordx4 %6, %14, off\n\t"
        "global_load_dwordx4 %7, %15, off\n\t"
        "s_waitcnt vmcnt(0)"
        : "=&v"(xv[0]), "=&v"(xv[1]), "=&v"(xv[2]), "=&v"(xv[3]),
          "=&v"(xv[4]), "=&v"(xv[5]), "=&v"(xv[6]), "=&v"(xv[7])
        : "v"(a0), "v"(a1), "v"(a2), "v"(a3),
          "v"(a4), "v"(a5), "v"(a6), "v"(a7)
        : "memory");

    float m[4], sc[4];
    #pragma unroll
    for (int k = 0; k < 4; ++k) { m[k] = 0.5f * thre; sc[k] = 0.0f; }

    #pragma unroll
    for (int t = 0; t < T1; ++t) {
        #pragma unroll
        for (int k = 0; k < 4; ++k) {
            m[k] += xv[t][k];
            const float spike = (m[k] - thre >= EPS_C) ? thre : 0.0f;
            m[k] -= spike;
            sc[k] += spike;
        }
    }

    #pragma unroll
    for (int t = 0; t < T1 - 1; ++t) {
        #pragma unroll
        for (int k = 0; k < 4; ++k) {
            const float spike = (m[k] - thre >= EPS_C) ? thre : 0.0f;
            const float rev   = (-m[k] > 0.0f) ? thre : 0.0f;
            m[k] = m[k] - spike + rev;
            sc[k] += spike - rev;
        }
    }

    fvec4 o;
    #pragma unroll
    for (int k = 0; k < 4; ++k) o[k] = sc[k];
    sc_out[i] = o;   // regular store: keep sc in L2/IF$ for kernel B
}

// ---- Kernel B: phase 3 closed form, one (frame, span) per block ----
// out[t][i] = thre * [ sc[i] - (t+1)*thre >= EPS ]  (exact at thre=2^-3).
// R8: REGULAR stores (the only variable changed vs R7).
__global__ __launch_bounds__(256) void if_phase3_kernel(
    const fvec4* __restrict__ sc_in,
    const float* __restrict__ thresh,
    fvec4* __restrict__ out,
    int n4)
{
    const int bid = blockIdx.x;
    const int t   = bid >> 10;
    const int s   = bid & 1023;
    const int base = s * 1024 + threadIdx.x;

    const float thre = thresh[0] / L_DIV;
    const float cut  = (float)(t + 1) * thre;   // exact for thre = 2^-3

    fvec4* outt = out + (size_t)t * n4;

    #pragma unroll
    for (int c = 0; c < 4; ++c) {
        const int i = base + c * 256;
        const fvec4 scv = sc_in[i];
        fvec4 o;
        #pragma unroll
        for (int k = 0; k < 4; ++k) {
            o[k] = (scv[k] - cut >= EPS_C) ? thre : 0.0f;
        }
        outt[i] = o;   // regular cached store (fill-path)
    }
}

// ---------------- Fallback: fused (R4, best single-kernel) ----------------
#define G 2
__global__ __launch_bounds__(256) void if_fused_kernel(
    const fvec4* __restrict__ x,
    const float* __restrict__ thresh,
    fvec4* __restrict__ out,
    int n4)
{
    const int base = blockIdx.x * (blockDim.x * G) + threadIdx.x;
    const float thre = thresh[0] / L_DIV;

    fvec4 xv[G][T1];
    #pragma unroll
    for (int t = 0; t < T1; ++t)
        #pragma unroll
        for (int g = 0; g < G; ++g)
            xv[g][t] = x[(size_t)t * n4 + base + g * 256];

    float m[G][4], sc[G][4];
    #pragma unroll
    for (int g = 0; g < G; ++g)
        #pragma unroll
        for (int k = 0; k < 4; ++k) { m[g][k] = 0.5f * thre; sc[g][k] = 0.0f; }

    #pragma unroll
    for (int t = 0; t < T1; ++t)
        #pragma unroll
        for (int g = 0; g < G; ++g)
            #pragma unroll
            for (int k = 0; k < 4; ++k) {
                m[g][k] += xv[g][t][k];
                const float spike = (m[g][k] - thre >= EPS_C) ? thre : 0.0f;
                m[g][k] -= spike;
                sc[g][k] += spike;
            }

    #pragma unroll
    for (int t = 0; t < T1 - 1; ++t)
        #pragma unroll
        for (int g = 0; g < G; ++g)
            #pragma unroll
            for (int k = 0; k < 4; ++k) {
                const float spike = (m[g][k] - thre >= EPS_C) ? thre : 0.0f;
                const float rev   = (-m[g][k] > 0.0f) ? thre : 0.0f;
                m[g][k] = m[g][k] - spike + rev;
                sc[g][k] += spike - rev;
            }

    #pragma unroll
    for (int t = 0; t < T2; ++t)
        #pragma unroll
        for (int g = 0; g < G; ++g) {
            fvec4 o;
            #pragma unroll
            for (int k = 0; k < 4; ++k) {
                const float spike = (sc[g][k] - thre >= EPS_C) ? thre : 0.0f;
                o[k] = spike;
                sc[g][k] -= spike;
            }
            __builtin_nontemporal_store(o, &out[(size_t)t * n4 + base + g * 256]);
        }
}

extern "C" void kernel_launch(void* const* d_in, const int* in_sizes, int n_in,
                              void* d_out, int out_size, void* d_ws, size_t ws_size,
                              hipStream_t stream) {
    const fvec4* x      = (const fvec4*)d_in[0];
    const float* thresh = (const float*)d_in[1];
    fvec4*       out    = (fvec4*)d_out;

    const int N  = in_sizes[0] / T1;  // 4,194,304
    const int n4 = N / 4;             // 1,048,576
    const int block = 256;

    const size_t sc_bytes = (size_t)N * sizeof(float);  // 16 MiB

    if (ws_size >= sc_bytes) {
        fvec4* sc = (fvec4*)d_ws;
        if_phase12_kernel<<<n4 / block, block, 0, stream>>>(x, thresh, sc, n4);
        if_phase3_kernel<<<(n4 / 1024) * T2, block, 0, stream>>>(sc, thresh, out, n4);
    } else {
        if_fused_kernel<<<n4 / (block * G), block, 0, stream>>>(x, thresh, out, n4);
    }
}

// Round 9
// 237.789 us; speedup vs baseline: 1.0529x; 1.0529x over previous
//
#include <hip/hip_runtime.h>

// Integrate-and-fire SNN forward (IF_88957362634870).
// x: 8 frames of N = 4,194,304 fp32 (16 MiB each); out: 8 frames.
//
// R0-R8 evidence: write side is fine (fill 6.5 TB/s; phase-3 kernel ~6 TB/s),
// but EVERY x-read structure (serial, burst, asm-forced) caps at ~2.3 TB/s.
// Theory: the 8 frame streams differ by exactly 2^24 B -> same HBM
// (channel,bank), different rows; keeping all 8 in flight = row thrash.
// R9: frame-sweep kernel A -- all 2048 blocks resident (8/CU), sweep frames
// sequentially in lockstep (prefetch t+1 only, __syncthreads per frame), so
// in-flight reads span <=2 frame regions at any instant.

#define T1 8
#define T2 8
#define L_DIV 8.0f
#define EPS_C (-8e-05f)

typedef float fvec4 __attribute__((ext_vector_type(4)));

// ---- Kernel A: phases 1+2 via lockstep frame sweep, x -> sc ----
// G=2 groups/thread -> 2048 blocks of 256 = 524288 threads; 8 blocks/CU,
// ALL resident simultaneously -> true device-wide frame lockstep.
__global__ __launch_bounds__(256) void if_phase12_sweep(
    const fvec4* __restrict__ x,
    const float* __restrict__ thresh,
    fvec4* __restrict__ sc_out,
    int n4)
{
    const int base = blockIdx.x * 512 + threadIdx.x;  // groups base, base+256
    const float thre = thresh[0] / L_DIV;

    float m[2][4], sc[2][4];
    #pragma unroll
    for (int g = 0; g < 2; ++g)
        #pragma unroll
        for (int k = 0; k < 4; ++k) { m[g][k] = 0.5f * thre; sc[g][k] = 0.0f; }

    // Prefetch frame 0.
    fvec4 cur0 = x[base];
    fvec4 cur1 = x[base + 256];

    #pragma unroll
    for (int t = 0; t < T1; ++t) {
        // Prefetch next frame (only region t+1 enters flight).
        fvec4 nxt0, nxt1;
        if (t < T1 - 1) {
            nxt0 = x[(size_t)(t + 1) * n4 + base];
            nxt1 = x[(size_t)(t + 1) * n4 + base + 256];
        }
        // Integrate current frame.
        #pragma unroll
        for (int k = 0; k < 4; ++k) {
            m[0][k] += cur0[k];
            float spike = (m[0][k] - thre >= EPS_C) ? thre : 0.0f;
            m[0][k] -= spike;
            sc[0][k] += spike;

            m[1][k] += cur1[k];
            spike = (m[1][k] - thre >= EPS_C) ? thre : 0.0f;
            m[1][k] -= spike;
            sc[1][k] += spike;
        }
        // Lockstep: keep the whole block (and, since all blocks are
        // resident and identical, the whole device) on the same frame.
        __syncthreads();
        cur0 = nxt0;
        cur1 = nxt1;
    }

    // Phase 2: 7 relaxation steps with reverse spikes (register-only).
    #pragma unroll
    for (int t = 0; t < T1 - 1; ++t) {
        #pragma unroll
        for (int g = 0; g < 2; ++g)
            #pragma unroll
            for (int k = 0; k < 4; ++k) {
                const float spike = (m[g][k] - thre >= EPS_C) ? thre : 0.0f;
                const float rev   = (-m[g][k] > 0.0f) ? thre : 0.0f;
                m[g][k] = m[g][k] - spike + rev;
                sc[g][k] += spike - rev;
            }
    }

    fvec4 o0, o1;
    #pragma unroll
    for (int k = 0; k < 4; ++k) { o0[k] = sc[0][k]; o1[k] = sc[1][k]; }
    sc_out[base]       = o0;
    sc_out[base + 256] = o1;
}

// ---- Kernel B: phase 3 closed form (R7, proven ~6 TB/s), sc -> out ----
// out[t][i] = thre * [ sc[i] - (t+1)*thre >= EPS ]  (exact at thre=2^-3:
// fires are a prefix in t and every subtraction is exact).
__global__ __launch_bounds__(256) void if_phase3_kernel(
    const fvec4* __restrict__ sc_in,
    const float* __restrict__ thresh,
    fvec4* __restrict__ out,
    int n4)
{
    const int bid = blockIdx.x;
    const int t   = bid >> 10;
    const int s   = bid & 1023;
    const int base = s * 1024 + threadIdx.x;

    const float thre = thresh[0] / L_DIV;
    const float cut  = (float)(t + 1) * thre;

    fvec4* outt = out + (size_t)t * n4;

    #pragma unroll
    for (int c = 0; c < 4; ++c) {
        const int i = base + c * 256;
        const fvec4 scv = sc_in[i];
        fvec4 o;
        #pragma unroll
        for (int k = 0; k < 4; ++k) {
            o[k] = (scv[k] - cut >= EPS_C) ? thre : 0.0f;
        }
        __builtin_nontemporal_store(o, &outt[i]);
    }
}

// ---------------- Fallback: fused (R4, best single-kernel) ----------------
#define G 2
__global__ __launch_bounds__(256) void if_fused_kernel(
    const fvec4* __restrict__ x,
    const float* __restrict__ thresh,
    fvec4* __restrict__ out,
    int n4)
{
    const int base = blockIdx.x * (blockDim.x * G) + threadIdx.x;
    const float thre = thresh[0] / L_DIV;

    fvec4 xv[G][T1];
    #pragma unroll
    for (int t = 0; t < T1; ++t)
        #pragma unroll
        for (int g = 0; g < G; ++g)
            xv[g][t] = x[(size_t)t * n4 + base + g * 256];

    float m[G][4], sc[G][4];
    #pragma unroll
    for (int g = 0; g < G; ++g)
        #pragma unroll
        for (int k = 0; k < 4; ++k) { m[g][k] = 0.5f * thre; sc[g][k] = 0.0f; }

    #pragma unroll
    for (int t = 0; t < T1; ++t)
        #pragma unroll
        for (int g = 0; g < G; ++g)
            #pragma unroll
            for (int k = 0; k < 4; ++k) {
                m[g][k] += xv[g][t][k];
                const float spike = (m[g][k] - thre >= EPS_C) ? thre : 0.0f;
                m[g][k] -= spike;
                sc[g][k] += spike;
            }

    #pragma unroll
    for (int t = 0; t < T1 - 1; ++t)
        #pragma unroll
        for (int g = 0; g < G; ++g)
            #pragma unroll
            for (int k = 0; k < 4; ++k) {
                const float spike = (m[g][k] - thre >= EPS_C) ? thre : 0.0f;
                const float rev   = (-m[g][k] > 0.0f) ? thre : 0.0f;
                m[g][k] = m[g][k] - spike + rev;
                sc[g][k] += spike - rev;
            }

    #pragma unroll
    for (int t = 0; t < T2; ++t)
        #pragma unroll
        for (int g = 0; g < G; ++g) {
            fvec4 o;
            #pragma unroll
            for (int k = 0; k < 4; ++k) {
                const float spike = (sc[g][k] - thre >= EPS_C) ? thre : 0.0f;
                o[k] = spike;
                sc[g][k] -= spike;
            }
            __builtin_nontemporal_store(o, &out[(size_t)t * n4 + base + g * 256]);
        }
}

extern "C" void kernel_launch(void* const* d_in, const int* in_sizes, int n_in,
                              void* d_out, int out_size, void* d_ws, size_t ws_size,
                              hipStream_t stream) {
    const fvec4* x      = (const fvec4*)d_in[0];
    const float* thresh = (const float*)d_in[1];
    fvec4*       out    = (fvec4*)d_out;

    const int N  = in_sizes[0] / T1;  // 4,194,304
    const int n4 = N / 4;             // 1,048,576
    const int block = 256;

    const size_t sc_bytes = (size_t)N * sizeof(float);  // 16 MiB

    if (ws_size >= sc_bytes) {
        fvec4* sc = (fvec4*)d_ws;
        // A: 2048 blocks (8/CU, all resident), lockstep frame sweep.
        if_phase12_sweep<<<n4 / 512, block, 0, stream>>>(x, thresh, sc, n4);
        // B: one (frame, span) per block, NT writes (R7 best).
        if_phase3_kernel<<<(n4 / 1024) * T2, block, 0, stream>>>(sc, thresh, out, n4);
    } else {
        if_fused_kernel<<<n4 / (block * G), block, 0, stream>>>(x, thresh, out, n4);
    }
}

// Round 10
// 225.829 us; speedup vs baseline: 1.1087x; 1.0530x over previous
//
#include <hip/hip_runtime.h>

// Integrate-and-fire SNN forward (IF_88957362634870).
// x: 8 frames of N = 4,194,304 fp32 (16 MiB each); out: 8 frames.
//
// Session evidence: write path does 6.6 TB/s (fill, phase-3 kernel), but
// every structure reading x from HBM/IF$ caps at 2.1-2.5 TB/s -- including
// the HIP runtime's own d_in restore copy (~2.8 TB/s combined). MLP, stream
// count, NT stores, and device-wide lockstep are all ruled out. Untested
// read-side variable: ~50% of reads hit IF$ (FETCH 65.5 of 134 MB). R10
// isolates it: nontemporal LOADS stream around L2/IF$ (FETCH should jump to
// ~134 MB). Also fold everything back into ONE kernel: elementwise op never
// needed the split; closed-form phase 3 (out[t][i] = thre*[sc[i] >=
// (t+1)*thre - eps], exact at thre=2^-3, verified R7/R8) + NT stores.

#define T1 8
#define T2 8
#define L_DIV 8.0f
#define EPS_C (-8e-05f)
#define G 2            // float4-groups per thread

typedef float fvec4 __attribute__((ext_vector_type(4)));

__global__ __launch_bounds__(256) void if_fwd_fused(
    const fvec4* __restrict__ x,
    const float* __restrict__ thresh,
    fvec4* __restrict__ out,
    int n4)
{
    const int base = blockIdx.x * (256 * G) + threadIdx.x;
    const float thre = thresh[0] / L_DIV;

    // All 16 loads nontemporal: stream around L2/IF$, straight from HBM.
    fvec4 xv[G][T1];
    #pragma unroll
    for (int t = 0; t < T1; ++t)
        #pragma unroll
        for (int g = 0; g < G; ++g)
            xv[g][t] = __builtin_nontemporal_load(&x[(size_t)t * n4 + base + g * 256]);

    float m[G][4], sc[G][4];
    #pragma unroll
    for (int g = 0; g < G; ++g)
        #pragma unroll
        for (int k = 0; k < 4; ++k) { m[g][k] = 0.5f * thre; sc[g][k] = 0.0f; }

    // Phase 1: integrate T1 frames, fire-and-subtract.
    #pragma unroll
    for (int t = 0; t < T1; ++t)
        #pragma unroll
        for (int g = 0; g < G; ++g)
            #pragma unroll
            for (int k = 0; k < 4; ++k) {
                m[g][k] += xv[g][t][k];
                const float spike = (m[g][k] - thre >= EPS_C) ? thre : 0.0f;
                m[g][k] -= spike;
                sc[g][k] += spike;
            }

    // Phase 2: 7 relaxation steps with reverse spikes (register-only).
    #pragma unroll
    for (int t = 0; t < T1 - 1; ++t)
        #pragma unroll
        for (int g = 0; g < G; ++g)
            #pragma unroll
            for (int k = 0; k < 4; ++k) {
                const float spike = (m[g][k] - thre >= EPS_C) ? thre : 0.0f;
                const float rev   = (-m[g][k] > 0.0f) ? thre : 0.0f;
                m[g][k] = m[g][k] - spike + rev;
                sc[g][k] += spike - rev;
            }

    // Phase 3 (closed form, verified R7/R8): fires are a prefix in t.
    // out[t][i] = thre * [ sc[i] - (t+1)*thre >= EPS ]; exact at thre=2^-3.
    #pragma unroll
    for (int t = 0; t < T2; ++t) {
        const float cut = (float)(t + 1) * thre;
        #pragma unroll
        for (int g = 0; g < G; ++g) {
            fvec4 o;
            #pragma unroll
            for (int k = 0; k < 4; ++k)
                o[k] = (sc[g][k] - cut >= EPS_C) ? thre : 0.0f;
            __builtin_nontemporal_store(o, &out[(size_t)t * n4 + base + g * 256]);
        }
    }
}

extern "C" void kernel_launch(void* const* d_in, const int* in_sizes, int n_in,
                              void* d_out, int out_size, void* d_ws, size_t ws_size,
                              hipStream_t stream) {
    const fvec4* x      = (const fvec4*)d_in[0];
    const float* thresh = (const float*)d_in[1];
    fvec4*       out    = (fvec4*)d_out;

    const int N  = in_sizes[0] / T1;  // 4,194,304
    const int n4 = N / 4;             // 1,048,576

    const int block = 256;
    const int grid  = n4 / (block * G);  // 2048
    if_fwd_fused<<<grid, block, 0, stream>>>(x, thresh, out, n4);
}